// Round 3
// baseline (154.919 us; speedup 1.0000x reference)
//
#include <hip/hip_runtime.h>

typedef unsigned short u16;
typedef unsigned int u32;

typedef __bf16 bf16x8 __attribute__((ext_vector_type(8)));
typedef float floatx4 __attribute__((ext_vector_type(4)));

// ---- helpers ----------------------------------------------------------------

__device__ __forceinline__ u32 f2bf(float f) {
    // round-to-nearest-even fp32 -> bf16 (bit pattern in low 16)
    u32 u = __builtin_bit_cast(u32, f);
    return (u + 0x7fffu + ((u >> 16) & 1u)) >> 16;
}

__device__ __forceinline__ float quant_w(float x) {
    // WAGE Quantize.W, BITS_W=2: clip to [-0.5,0.5], round to grid step 0.5 (RNE)
    float xc = fminf(fmaxf(x, -0.5f), 0.5f);
    return rintf(xc * 2.0f) * 0.5f;
}

__device__ __forceinline__ void gload_lds16(const u16* g, u16* l) {
    __builtin_amdgcn_global_load_lds(
        (const __attribute__((address_space(1))) void*)g,
        (__attribute__((address_space(3))) void*)l,
        16, 0, 0);
}

// ---- kernel 1: fused A-cast (blocks 0..8191) + W quant+transpose (8192..9215)

__global__ __launch_bounds__(256) void prep_kernel(const float4* __restrict__ Af,
                                                   uint4* __restrict__ Abf,
                                                   const float* __restrict__ W,
                                                   u16* __restrict__ Bt) {
    const int bid = blockIdx.x;
    const int tid = threadIdx.x;
    if (bid < 8192) {
        // cast A fp32 -> bf16, 8 floats / thread
        int t = bid * 256 + tid;
        float4 a = Af[2 * t];
        float4 b = Af[2 * t + 1];
        uint4 o;
        o.x = f2bf(a.x) | (f2bf(a.y) << 16);
        o.y = f2bf(a.z) | (f2bf(a.w) << 16);
        o.z = f2bf(b.x) | (f2bf(b.y) << 16);
        o.w = f2bf(b.z) | (f2bf(b.w) << 16);
        Abf[t] = o;
    } else {
        // quantize + transpose W[k][n] -> Bt[n][k]
        __shared__ u16 tile[32][33];
        const int KN = 1024;
        int b = bid - 8192;          // 0..1023
        int n0 = (b & 31) * 32;
        int k0 = (b >> 5) * 32;
        int tx = tid & 31;           // 0..31
        int ty = tid >> 5;           // 0..7
#pragma unroll
        for (int i = 0; i < 4; i++) {
            int kl = ty + i * 8;
            float x = W[(k0 + kl) * KN + n0 + tx];
            tile[kl][tx] = (u16)f2bf(quant_w(x));
        }
        __syncthreads();
#pragma unroll
        for (int i = 0; i < 4; i++) {
            int nl = ty + i * 8;
            Bt[(n0 + nl) * KN + k0 + tx] = tile[tx][nl];
        }
    }
}

// ---- kernel 2: C[M][N] = A[M][K] * Bt[N][K]^T  (bf16 MFMA, fp32 out) --------
// 128x128 tile, BK=32, SINGLE-barrier double-buffered K-loop: loads for tile
// k+1 are issued right after the barrier, compute on tile k overlaps them, so
// the vmcnt(0) drain at the next barrier finds them already landed.
// XOR bank-swizzle (2-bit, 2-way max = free), grid x = M-blocks for L2 locality.

__global__ __launch_bounds__(256) void gemm_bt_kernel(const u16* __restrict__ A,
                                                      const u16* __restrict__ Bt,
                                                      float* __restrict__ C) {
    const int K = 1024;
    const int N = 1024;

    __shared__ alignas(16) u16 As[2][128 * 32];  // 2 x 8 KB
    __shared__ alignas(16) u16 Bs[2][128 * 32];  // 2 x 8 KB

    const int tid = threadIdx.x;
    const int mbase = blockIdx.x * 128;   // x = M: XCD (id%8) gets L2-resident slice
    const int nbase = blockIdx.y * 128;
    const int lane = tid & 63;
    const int wv = tid >> 6;
    const int wm = (wv & 1) * 64;
    const int wn = (wv >> 1) * 64;
    const int frow = lane & 15;           // m (or n) index within 16-tile
    const int fkc = lane >> 4;            // logical k-chunk (0..3) within BK=32
    const int koff = ((fkc ^ ((frow >> 1) & 3)) * 8);  // swizzled LDS k-offset

    // staging: thread t stages chunks c0=t, c1=t+256 (of 512 16B-chunks/tile)
    // chunk c: row=c>>2, linear kc=c&3, global kc = (c&3) ^ ((row>>1)&3)
    const int c0 = tid, c1 = tid + 256;
    const int r0 = c0 >> 2, r1 = c1 >> 2;
    const int g0 = (c0 & 3) ^ ((r0 >> 1) & 3);
    const int g1 = (c1 & 3) ^ ((r1 >> 1) & 3);
    const u16* Ag0 = &A[(size_t)(mbase + r0) * K + g0 * 8];
    const u16* Ag1 = &A[(size_t)(mbase + r1) * K + g1 * 8];
    const u16* Bg0 = &Bt[(size_t)(nbase + r0) * K + g0 * 8];
    const u16* Bg1 = &Bt[(size_t)(nbase + r1) * K + g1 * 8];

    floatx4 acc[4][4] = {};

    // prologue: fill buffer 0 for kt=0
    gload_lds16(Ag0, &As[0][c0 * 8]);
    gload_lds16(Ag1, &As[0][c1 * 8]);
    gload_lds16(Bg0, &Bs[0][c0 * 8]);
    gload_lds16(Bg1, &Bs[0][c1 * 8]);

    for (int it = 0; it < 32; ++it) {
        __syncthreads();  // publishes buf[it&1] loads; proves buf[1-it&1] readers done
        const int cur = it & 1;
        const int nxt = cur ^ 1;
        if (it + 1 < 32) {
            const int kt = (it + 1) * 32;
            gload_lds16(Ag0 + kt, &As[nxt][c0 * 8]);
            gload_lds16(Ag1 + kt, &As[nxt][c1 * 8]);
            gload_lds16(Bg0 + kt, &Bs[nxt][c0 * 8]);
            gload_lds16(Bg1 + kt, &Bs[nxt][c1 * 8]);
        }

        bf16x8 af[4], bf[4];
#pragma unroll
        for (int i = 0; i < 4; i++)
            af[i] = *(const bf16x8*)&As[cur][(wm + i * 16 + frow) * 32 + koff];
#pragma unroll
        for (int j = 0; j < 4; j++)
            bf[j] = *(const bf16x8*)&Bs[cur][(wn + j * 16 + frow) * 32 + koff];
#pragma unroll
        for (int i = 0; i < 4; i++)
#pragma unroll
            for (int j = 0; j < 4; j++)
                acc[i][j] = __builtin_amdgcn_mfma_f32_16x16x32_bf16(
                    af[i], bf[j], acc[i][j], 0, 0, 0);
    }

    // epilogue: C/D layout col = lane&15, row = (lane>>4)*4 + reg
    const int crow = (lane >> 4) * 4;
    const int ccol = lane & 15;
#pragma unroll
    for (int i = 0; i < 4; i++) {
#pragma unroll
        for (int j = 0; j < 4; j++) {
            float* cp = &C[(size_t)(mbase + wm + i * 16 + crow) * N + nbase + wn + j * 16 + ccol];
#pragma unroll
            for (int r = 0; r < 4; r++) cp[r * N] = acc[i][j][r];
        }
    }
}

// ---- launch -----------------------------------------------------------------

extern "C" void kernel_launch(void* const* d_in, const int* in_sizes, int n_in,
                              void* d_out, int out_size, void* d_ws, size_t ws_size,
                              hipStream_t stream) {
    const float* A = (const float*)d_in[0];   // 16384 x 1024
    const float* W = (const float*)d_in[1];   // 1024 x 1024
    float* C = (float*)d_out;                 // 16384 x 1024

    u16* Abf = (u16*)d_ws;                                   // 32 MB
    u16* Btq = (u16*)((char*)d_ws + (size_t)33554432);       // 2 MB

    prep_kernel<<<8192 + 1024, 256, 0, stream>>>((const float4*)A, (uint4*)Abf, W, Btq);
    gemm_bt_kernel<<<dim3(128, 8), 256, 0, stream>>>(Abf, Btq, C);
}